// Round 2
// baseline (121.471 us; speedup 1.0000x reference)
//
#include <hip/hip_runtime.h>

// HMM posterior: out[b,t,s] = log_softmax_s(alphahat[t]+betahat[t]) — batch-independent
// (per-(b,t) scalar emission terms cancel in the state-axis softmax; observations unused).
// Linear space with max-rescale (scale cancels): p_t = p0 @ E^t, q_t = E^(T-1-t) @ 1, E=exp(A).
//
// K1 hmm_powers: M[k]=norm(E^(2^k)), Mt[k]=transpose — 9 serial 64^3 LDS GEMMs, 1 block.
// K2 hmm_rows:   per-t binary-decomposition matvecs -> SG[t][64] log-softmax rows (ws).
// K3 hmm_bcast:  SG (256 KB, L2-hot) broadcast to out (64 MB), contiguous 32 KB/block.

#define TT 1024
#define NK 10

__device__ __forceinline__ void fma4(float4& acc, float a, float4 b) {
    acc.x = fmaf(a, b.x, acc.x);
    acc.y = fmaf(a, b.y, acc.y);
    acc.z = fmaf(a, b.z, acc.z);
    acc.w = fmaf(a, b.w, acc.w);
}

__global__ __launch_bounds__(256) void hmm_powers(const float* __restrict__ logA,
                                                  float* __restrict__ M,
                                                  float* __restrict__ Mt) {
    const int LD = 68;                    // padded LDS stride, 16B-aligned rows
    __shared__ float bufA[64 * 68];
    __shared__ float bufB[64 * 68];
    __shared__ float red4[4];
    const int tid  = threadIdx.x;
    const int wid  = tid >> 6;
    const int lane = tid & 63;

    // M0 = exp(logA) normalized by its max entry (wave shfl-reduce, 1 barrier)
    float4 ev[4];
    float lmax = 0.f;
    #pragma unroll
    for (int c = 0; c < 4; ++c) {
        float4 v = ((const float4*)logA)[tid + 256 * c];
        float4 w;
        w.x = __expf(v.x); w.y = __expf(v.y); w.z = __expf(v.z); w.w = __expf(v.w);
        ev[c] = w;
        lmax = fmaxf(lmax, fmaxf(fmaxf(w.x, w.y), fmaxf(w.z, w.w)));
    }
    #pragma unroll
    for (int off = 32; off > 0; off >>= 1)
        lmax = fmaxf(lmax, __shfl_xor(lmax, off, 64));
    if (lane == 0) red4[wid] = lmax;
    __syncthreads();
    const float scale0 = 1.f / fmaxf(fmaxf(red4[0], red4[1]), fmaxf(red4[2], red4[3]));
    #pragma unroll
    for (int c = 0; c < 4; ++c) {
        int f = tid + 256 * c;            // float4 index; 4 elements share one row
        int idx = f * 4;
        int i = idx >> 6;
        int j = idx & 63;
        float4 w = ev[c];
        w.x *= scale0; w.y *= scale0; w.z *= scale0; w.w *= scale0;
        *(float4*)&bufA[i * LD + j] = w;
        ((float4*)M)[f] = w;
        Mt[(j + 0) * 64 + i] = w.x;
        Mt[(j + 1) * 64 + i] = w.y;
        Mt[(j + 2) * 64 + i] = w.z;
        Mt[(j + 3) * 64 + i] = w.w;
    }

    float* cur = bufA;
    float* nxt = bufB;
    const int r0 = (tid >> 4) * 4, j0 = (tid & 15) * 4;

    for (int k = 1; k < NK; ++k) {
        __syncthreads();                  // cur fully written
        float4 acc0 = make_float4(0.f, 0.f, 0.f, 0.f);
        float4 acc1 = acc0, acc2 = acc0, acc3 = acc0;
        #pragma unroll
        for (int i0 = 0; i0 < 64; i0 += 4) {
            float4 a0 = *(const float4*)&cur[(r0 + 0) * LD + i0];
            float4 a1 = *(const float4*)&cur[(r0 + 1) * LD + i0];
            float4 a2 = *(const float4*)&cur[(r0 + 2) * LD + i0];
            float4 a3 = *(const float4*)&cur[(r0 + 3) * LD + i0];
            float4 b0 = *(const float4*)&cur[(i0 + 0) * LD + j0];
            float4 b1 = *(const float4*)&cur[(i0 + 1) * LD + j0];
            float4 b2 = *(const float4*)&cur[(i0 + 2) * LD + j0];
            float4 b3 = *(const float4*)&cur[(i0 + 3) * LD + j0];
            fma4(acc0, a0.x, b0); fma4(acc0, a0.y, b1); fma4(acc0, a0.z, b2); fma4(acc0, a0.w, b3);
            fma4(acc1, a1.x, b0); fma4(acc1, a1.y, b1); fma4(acc1, a1.z, b2); fma4(acc1, a1.w, b3);
            fma4(acc2, a2.x, b0); fma4(acc2, a2.y, b1); fma4(acc2, a2.z, b2); fma4(acc2, a2.w, b3);
            fma4(acc3, a3.x, b0); fma4(acc3, a3.y, b1); fma4(acc3, a3.z, b2); fma4(acc3, a3.w, b3);
        }
        float m0 = fmaxf(fmaxf(acc0.x, acc0.y), fmaxf(acc0.z, acc0.w));
        float m1 = fmaxf(fmaxf(acc1.x, acc1.y), fmaxf(acc1.z, acc1.w));
        float m2 = fmaxf(fmaxf(acc2.x, acc2.y), fmaxf(acc2.z, acc2.w));
        float m3 = fmaxf(fmaxf(acc3.x, acc3.y), fmaxf(acc3.z, acc3.w));
        float m = fmaxf(fmaxf(m0, m1), fmaxf(m2, m3));
        #pragma unroll
        for (int off = 32; off > 0; off >>= 1)
            m = fmaxf(m, __shfl_xor(m, off, 64));
        if (lane == 0) red4[wid] = m;
        __syncthreads();                  // red4 ready; all GEMM reads of cur done
        const float sc = 1.f / fmaxf(fmaxf(red4[0], red4[1]), fmaxf(red4[2], red4[3]));
        float* Mk  = M  + (k << 12);
        float* Mtk = Mt + (k << 12);
        float4 accs[4] = {acc0, acc1, acc2, acc3};
        #pragma unroll
        for (int rr = 0; rr < 4; ++rr) {
            float4 w = accs[rr];
            w.x *= sc; w.y *= sc; w.z *= sc; w.w *= sc;
            *(float4*)&nxt[(r0 + rr) * LD + j0] = w;
            *(float4*)&Mk[(r0 + rr) * 64 + j0] = w;
            Mtk[(j0 + 0) * 64 + r0 + rr] = w.x;
            Mtk[(j0 + 1) * 64 + r0 + rr] = w.y;
            Mtk[(j0 + 2) * 64 + r0 + rr] = w.z;
            Mtk[(j0 + 3) * 64 + r0 + rr] = w.w;
        }
        float* tmp = cur; cur = nxt; nxt = tmp;
    }
}

// 1024 blocks x 128 threads: wave 0 -> p_t, wave 1 -> q_t, then log-softmax row -> SG[t].
__global__ __launch_bounds__(128) void hmm_rows(const float* __restrict__ M,
                                                const float* __restrict__ Mt,
                                                const float* __restrict__ logInit,
                                                float* __restrict__ SG) {
    const int t = blockIdx.x;
    __shared__ float sp[64];
    __shared__ float sq[64];
    const int lane = threadIdx.x & 63;
    const int w    = threadIdx.x >> 6;

    if (w == 0) {
        sp[lane] = __expf(logInit[lane]);
        const int e = t;
        for (int k = 0; k < NK; ++k) {
            if ((e >> k) & 1) {
                const float* Mk = M + (k << 12);
                float a0 = 0.f, a1 = 0.f, a2 = 0.f, a3 = 0.f;
                #pragma unroll
                for (int i = 0; i < 16; ++i) {
                    a0 = fmaf(sp[i],      Mk[( i       << 6) + lane], a0);
                    a1 = fmaf(sp[i + 16], Mk[((i + 16) << 6) + lane], a1);
                    a2 = fmaf(sp[i + 32], Mk[((i + 32) << 6) + lane], a2);
                    a3 = fmaf(sp[i + 48], Mk[((i + 48) << 6) + lane], a3);
                }
                float acc = (a0 + a1) + (a2 + a3);
                float mx = acc;
                #pragma unroll
                for (int off = 32; off > 0; off >>= 1)
                    mx = fmaxf(mx, __shfl_xor(mx, off, 64));
                sp[lane] = acc * (1.f / mx);
            }
        }
    } else {
        sq[lane] = 1.f;
        const int e = (TT - 1) - t;
        for (int k = 0; k < NK; ++k) {
            if ((e >> k) & 1) {
                const float* Mk = Mt + (k << 12);
                float a0 = 0.f, a1 = 0.f, a2 = 0.f, a3 = 0.f;
                #pragma unroll
                for (int i = 0; i < 16; ++i) {
                    a0 = fmaf(sq[i],      Mk[( i       << 6) + lane], a0);
                    a1 = fmaf(sq[i + 16], Mk[((i + 16) << 6) + lane], a1);
                    a2 = fmaf(sq[i + 32], Mk[((i + 32) << 6) + lane], a2);
                    a3 = fmaf(sq[i + 48], Mk[((i + 48) << 6) + lane], a3);
                }
                float acc = (a0 + a1) + (a2 + a3);
                float mx = acc;
                #pragma unroll
                for (int off = 32; off > 0; off >>= 1)
                    mx = fmaxf(mx, __shfl_xor(mx, off, 64));
                sq[lane] = acc * (1.f / mx);
            }
        }
    }
    __syncthreads();

    if (w == 0) {
        float gv = __logf(sp[lane]) + __logf(sq[lane]);
        float mx = gv;
        #pragma unroll
        for (int off = 32; off > 0; off >>= 1)
            mx = fmaxf(mx, __shfl_xor(mx, off, 64));
        float ex = __expf(gv - mx);
        float sm = ex;
        #pragma unroll
        for (int off = 32; off > 0; off >>= 1)
            sm += __shfl_xor(sm, off, 64);
        SG[(t << 6) + lane] = gv - mx - __logf(sm);
    }
}

// 2048 blocks x 256 threads: block (b, tc) copies SG[tc*128 .. tc*128+127] rows to
// out[b][tc*128 .. ][.], a contiguous 32 KB span. float4 throughout.
__global__ __launch_bounds__(256) void hmm_bcast(const float* __restrict__ SG,
                                                 float* __restrict__ out) {
    const int c  = blockIdx.x;
    const int b  = c >> 3;
    const int tc = c & 7;
    const float4* s4 = (const float4*)SG + ((size_t)tc << 11);
    float4*       o4 = (float4*)out + ((size_t)b << 14) + ((size_t)tc << 11);
    const int tid = threadIdx.x;
    #pragma unroll
    for (int it = 0; it < 8; ++it) {
        int f = tid + (it << 8);
        o4[f] = s4[f];
    }
}

extern "C" void kernel_launch(void* const* d_in, const int* in_sizes, int n_in,
                              void* d_out, int out_size, void* d_ws, size_t ws_size,
                              hipStream_t stream) {
    // inputs: [0] observations (unused), [1] log_transition (64x64 f32),
    //         [2] log_initial (64 f32), [3] log_emission (unused)
    const float* logA    = (const float*)d_in[1];
    const float* logInit = (const float*)d_in[2];
    float* M  = (float*)d_ws;              // 10 * 4096 floats
    float* Mt = M + NK * 4096;             // 10 * 4096 floats
    float* SG = Mt + NK * 4096;            // 1024 * 64 floats (total ~576 KB of ws)
    hmm_powers<<<1, 256, 0, stream>>>(logA, M, Mt);
    hmm_rows<<<TT, 128, 0, stream>>>(M, Mt, logInit, SG);
    hmm_bcast<<<2048, 256, 0, stream>>>(SG, (float*)d_out);
}

// Round 3
// 109.771 us; speedup vs baseline: 1.1066x; 1.1066x over previous
//
#include <hip/hip_runtime.h>

// HMM posterior: out[b,t,s] = log_softmax_s(alphahat[t]+betahat[t]) — batch-independent
// (per-(b,t) scalar emission terms cancel in the state-axis softmax; observations unused).
// Linear space with max-rescale (scale cancels): p_t = p0 @ E^t, q_t = E^(T-1-t) @ 1, E=exp(A).
//
// K1 hmm_powers: M[k]=norm(E^(2^k)) + transposes via SPLIT-BF16 MFMA squarings
//                (X ~ hi+lo bf16; D = Ah*Bh + Ah*Bl + Al*Bh; rel err ~1e-5/squaring).
// K2 hmm_rows:   per-t binary-decomposition matvecs -> SG[t][64] log-softmax rows.
// K3 hmm_bcast:  SG (256 KB, L2-hot) broadcast to out (64 MB), contiguous 32 KB/block.

#define TT 1024
#define NK 10
#define PS 72   // bf16 plane stride in ushorts (144 B rows: 16B-aligned, 2-way banks = free)

typedef short  bf16x8 __attribute__((ext_vector_type(8)));
typedef float  f32x4  __attribute__((ext_vector_type(4)));

__device__ __forceinline__ unsigned short f2bf(float x) {
    unsigned u = __float_as_uint(x);
    unsigned r = u + 0x7fffu + ((u >> 16) & 1u);   // RNE; inputs finite
    return (unsigned short)(r >> 16);
}
__device__ __forceinline__ float bf2f(unsigned short h) {
    return __uint_as_float(((unsigned)h) << 16);
}

__global__ __launch_bounds__(256) void hmm_powers(const float* __restrict__ logA,
                                                  float* __restrict__ M,
                                                  float* __restrict__ Mt) {
    __shared__ unsigned short Ah[64 * PS], Al[64 * PS];   // row-major hi/lo planes
    __shared__ unsigned short Th[64 * PS], Tl[64 * PS];   // transposed hi/lo planes
    __shared__ float red4[4];
    const int tid  = threadIdx.x;
    const int wid  = tid >> 6;
    const int lane = tid & 63;

    // ---- E0 = exp(logA), normalized by max entry; emit fp32 M[0]/Mt[0] + bf16 planes.
    {
        const int row = tid >> 2;
        const int c0  = (tid & 3) * 16;
        float v[16];
        float lmax = 0.f;
        #pragma unroll
        for (int jj = 0; jj < 4; ++jj) {
            float4 x = ((const float4*)logA)[row * 16 + (tid & 3) * 4 + jj];
            float e0 = __expf(x.x), e1 = __expf(x.y), e2 = __expf(x.z), e3 = __expf(x.w);
            v[4 * jj + 0] = e0; v[4 * jj + 1] = e1; v[4 * jj + 2] = e2; v[4 * jj + 3] = e3;
            lmax = fmaxf(lmax, fmaxf(fmaxf(e0, e1), fmaxf(e2, e3)));
        }
        #pragma unroll
        for (int off = 32; off > 0; off >>= 1)
            lmax = fmaxf(lmax, __shfl_xor(lmax, off, 64));
        if (lane == 0) red4[wid] = lmax;
        __syncthreads();
        const float sc = 1.f / fmaxf(fmaxf(red4[0], red4[1]), fmaxf(red4[2], red4[3]));
        #pragma unroll
        for (int j = 0; j < 16; ++j) {
            float val = v[j] * sc;
            unsigned short hi = f2bf(val);
            unsigned short lo = f2bf(val - bf2f(hi));
            int cc = c0 + j;
            Ah[row * PS + cc] = hi;  Al[row * PS + cc] = lo;
            Th[cc * PS + row] = hi;  Tl[cc * PS + row] = lo;
            M [row * 64 + cc] = val;
            Mt[cc * 64 + row] = val;
        }
    }

    const int quad = (lane >> 4);
    const int l15  = lane & 15;

    // ---- 9 serial squarings, each: 24 MFMA/wave + hi/lo plane rewrite.
    for (int k = 1; k < NK; ++k) {
        __syncthreads();                       // planes (and red4 reuse) ready
        f32x4 acc[4];
        #pragma unroll
        for (int c = 0; c < 4; ++c) acc[c] = (f32x4){0.f, 0.f, 0.f, 0.f};
        #pragma unroll
        for (int kk = 0; kk < 2; ++kk) {
            const int ao = (16 * wid + l15) * PS + 32 * kk + quad * 8;
            bf16x8 ah = *(const bf16x8*)&Ah[ao];
            bf16x8 al = *(const bf16x8*)&Al[ao];
            #pragma unroll
            for (int c = 0; c < 4; ++c) {
                const int bo = (16 * c + l15) * PS + 32 * kk + quad * 8;
                bf16x8 bh = *(const bf16x8*)&Th[bo];
                bf16x8 bl = *(const bf16x8*)&Tl[bo];
                acc[c] = __builtin_amdgcn_mfma_f32_16x16x32_bf16(ah, bh, acc[c], 0, 0, 0);
                acc[c] = __builtin_amdgcn_mfma_f32_16x16x32_bf16(ah, bl, acc[c], 0, 0, 0);
                acc[c] = __builtin_amdgcn_mfma_f32_16x16x32_bf16(al, bh, acc[c], 0, 0, 0);
            }
        }
        float m = 0.f;
        #pragma unroll
        for (int c = 0; c < 4; ++c)
            #pragma unroll
            for (int r = 0; r < 4; ++r) m = fmaxf(m, acc[c][r]);
        #pragma unroll
        for (int off = 32; off > 0; off >>= 1)
            m = fmaxf(m, __shfl_xor(m, off, 64));
        if (lane == 0) red4[wid] = m;
        __syncthreads();
        const float sc = 1.f / fmaxf(fmaxf(red4[0], red4[1]), fmaxf(red4[2], red4[3]));
        float* Mk  = M  + (k << 12);
        float* Mtk = Mt + (k << 12);
        #pragma unroll
        for (int c = 0; c < 4; ++c) {
            #pragma unroll
            for (int r = 0; r < 4; ++r) {
                float val = acc[c][r] * sc;
                const int rr = 16 * wid + quad * 4 + r;   // C/D: row = quad*4+reg (m89)
                const int cc = 16 * c   + l15;            //      col = lane&15
                Mk [rr * 64 + cc] = val;
                Mtk[cc * 64 + rr] = val;
                if (k < NK - 1) {
                    unsigned short hi = f2bf(val);
                    unsigned short lo = f2bf(val - bf2f(hi));
                    Ah[rr * PS + cc] = hi;  Al[rr * PS + cc] = lo;
                    Th[cc * PS + rr] = hi;  Tl[cc * PS + rr] = lo;
                }
            }
        }
    }
}

// 1024 blocks x 128 threads: wave 0 -> p_t, wave 1 -> q_t, then log-softmax row -> SG[t].
__global__ __launch_bounds__(128) void hmm_rows(const float* __restrict__ M,
                                                const float* __restrict__ Mt,
                                                const float* __restrict__ logInit,
                                                float* __restrict__ SG) {
    const int t = blockIdx.x;
    __shared__ float sp[64];
    __shared__ float sq[64];
    const int lane = threadIdx.x & 63;
    const int w    = threadIdx.x >> 6;

    if (w == 0) {
        sp[lane] = __expf(logInit[lane]);
        const int e = t;
        for (int k = 0; k < NK; ++k) {
            if ((e >> k) & 1) {
                const float* Mk = M + (k << 12);
                float a0 = 0.f, a1 = 0.f, a2 = 0.f, a3 = 0.f;
                #pragma unroll
                for (int i = 0; i < 16; ++i) {
                    a0 = fmaf(sp[i],      Mk[( i       << 6) + lane], a0);
                    a1 = fmaf(sp[i + 16], Mk[((i + 16) << 6) + lane], a1);
                    a2 = fmaf(sp[i + 32], Mk[((i + 32) << 6) + lane], a2);
                    a3 = fmaf(sp[i + 48], Mk[((i + 48) << 6) + lane], a3);
                }
                float acc = (a0 + a1) + (a2 + a3);
                float mx = acc;
                #pragma unroll
                for (int off = 32; off > 0; off >>= 1)
                    mx = fmaxf(mx, __shfl_xor(mx, off, 64));
                sp[lane] = acc * (1.f / mx);
            }
        }
    } else {
        sq[lane] = 1.f;
        const int e = (TT - 1) - t;
        for (int k = 0; k < NK; ++k) {
            if ((e >> k) & 1) {
                const float* Mk = Mt + (k << 12);
                float a0 = 0.f, a1 = 0.f, a2 = 0.f, a3 = 0.f;
                #pragma unroll
                for (int i = 0; i < 16; ++i) {
                    a0 = fmaf(sq[i],      Mk[( i       << 6) + lane], a0);
                    a1 = fmaf(sq[i + 16], Mk[((i + 16) << 6) + lane], a1);
                    a2 = fmaf(sq[i + 32], Mk[((i + 32) << 6) + lane], a2);
                    a3 = fmaf(sq[i + 48], Mk[((i + 48) << 6) + lane], a3);
                }
                float acc = (a0 + a1) + (a2 + a3);
                float mx = acc;
                #pragma unroll
                for (int off = 32; off > 0; off >>= 1)
                    mx = fmaxf(mx, __shfl_xor(mx, off, 64));
                sq[lane] = acc * (1.f / mx);
            }
        }
    }
    __syncthreads();

    if (w == 0) {
        float gv = __logf(sp[lane]) + __logf(sq[lane]);
        float mx = gv;
        #pragma unroll
        for (int off = 32; off > 0; off >>= 1)
            mx = fmaxf(mx, __shfl_xor(mx, off, 64));
        float ex = __expf(gv - mx);
        float sm = ex;
        #pragma unroll
        for (int off = 32; off > 0; off >>= 1)
            sm += __shfl_xor(sm, off, 64);
        SG[(t << 6) + lane] = gv - mx - __logf(sm);
    }
}

// 2048 blocks x 256 threads: block (b, tc) copies SG rows into out[b], contiguous 32 KB.
__global__ __launch_bounds__(256) void hmm_bcast(const float* __restrict__ SG,
                                                 float* __restrict__ out) {
    const int c  = blockIdx.x;
    const int b  = c >> 3;
    const int tc = c & 7;
    const float4* s4 = (const float4*)SG + ((size_t)tc << 11);
    float4*       o4 = (float4*)out + ((size_t)b << 14) + ((size_t)tc << 11);
    const int tid = threadIdx.x;
    #pragma unroll
    for (int it = 0; it < 8; ++it) {
        int f = tid + (it << 8);
        o4[f] = s4[f];
    }
}

extern "C" void kernel_launch(void* const* d_in, const int* in_sizes, int n_in,
                              void* d_out, int out_size, void* d_ws, size_t ws_size,
                              hipStream_t stream) {
    // inputs: [0] observations (unused), [1] log_transition (64x64 f32),
    //         [2] log_initial (64 f32), [3] log_emission (unused)
    const float* logA    = (const float*)d_in[1];
    const float* logInit = (const float*)d_in[2];
    float* M  = (float*)d_ws;              // 10 * 4096 floats
    float* Mt = M + NK * 4096;             // 10 * 4096 floats
    float* SG = Mt + NK * 4096;            // 1024 * 64 floats
    hmm_powers<<<1, 256, 0, stream>>>(logA, M, Mt);
    hmm_rows<<<TT, 128, 0, stream>>>(M, Mt, logInit, SG);
    hmm_bcast<<<2048, 256, 0, stream>>>(SG, (float*)d_out);
}

// Round 4
// 104.414 us; speedup vs baseline: 1.1634x; 1.0513x over previous
//
#include <hip/hip_runtime.h>

// HMM posterior: out[b,t,s] = log_softmax_s(alphahat[t]+betahat[t]) — batch-independent
// (per-(b,t) scalar emission terms cancel in the state-axis softmax; observations unused).
// Linear space with max-rescale (scale cancels): p_t = p0 @ E^t, q_t = E^(T-1-t) @ 1, E=exp(A).
//
// K1 hmm_powers: M[k]=norm(E^(2^k)) + transposes via SPLIT-BF16 MFMA squarings
//                (X ~ hi+lo bf16; D = Ah*Bh + Ah*Bl + Al*Bh; rel err ~1e-5/squaring).
// K2 hmm_fused:  per-t binary-decomposition matvecs (L2-hot M/Mt) -> log-softmax row
//                -> broadcast-write 64 KB of out. Write-roofline bound (64 MB total).

#define TT 1024
#define NK 10
#define PS 72   // bf16 plane stride in ushorts (144 B rows: 16B-aligned, 2-way banks = free)

typedef short  bf16x8 __attribute__((ext_vector_type(8)));
typedef float  f32x4  __attribute__((ext_vector_type(4)));

__device__ __forceinline__ unsigned short f2bf(float x) {
    unsigned u = __float_as_uint(x);
    unsigned r = u + 0x7fffu + ((u >> 16) & 1u);   // RNE; inputs finite
    return (unsigned short)(r >> 16);
}
__device__ __forceinline__ float bf2f(unsigned short h) {
    return __uint_as_float(((unsigned)h) << 16);
}

__global__ __launch_bounds__(256) void hmm_powers(const float* __restrict__ logA,
                                                  float* __restrict__ M,
                                                  float* __restrict__ Mt) {
    __shared__ unsigned short Ah[64 * PS], Al[64 * PS];   // row-major hi/lo planes
    __shared__ unsigned short Th[64 * PS], Tl[64 * PS];   // transposed hi/lo planes
    __shared__ float red4[4];
    const int tid  = threadIdx.x;
    const int wid  = tid >> 6;
    const int lane = tid & 63;

    // ---- E0 = exp(logA), normalized by max entry; emit fp32 M[0]/Mt[0] + bf16 planes.
    {
        const int row = tid >> 2;
        const int c0  = (tid & 3) * 16;
        float v[16];
        float lmax = 0.f;
        #pragma unroll
        for (int jj = 0; jj < 4; ++jj) {
            float4 x = ((const float4*)logA)[row * 16 + (tid & 3) * 4 + jj];
            float e0 = __expf(x.x), e1 = __expf(x.y), e2 = __expf(x.z), e3 = __expf(x.w);
            v[4 * jj + 0] = e0; v[4 * jj + 1] = e1; v[4 * jj + 2] = e2; v[4 * jj + 3] = e3;
            lmax = fmaxf(lmax, fmaxf(fmaxf(e0, e1), fmaxf(e2, e3)));
        }
        #pragma unroll
        for (int off = 32; off > 0; off >>= 1)
            lmax = fmaxf(lmax, __shfl_xor(lmax, off, 64));
        if (lane == 0) red4[wid] = lmax;
        __syncthreads();
        const float sc = 1.f / fmaxf(fmaxf(red4[0], red4[1]), fmaxf(red4[2], red4[3]));
        #pragma unroll
        for (int j = 0; j < 16; ++j) {
            float val = v[j] * sc;
            unsigned short hi = f2bf(val);
            unsigned short lo = f2bf(val - bf2f(hi));
            int cc = c0 + j;
            Ah[row * PS + cc] = hi;  Al[row * PS + cc] = lo;
            Th[cc * PS + row] = hi;  Tl[cc * PS + row] = lo;
            M [row * 64 + cc] = val;
            Mt[cc * 64 + row] = val;
        }
    }

    const int quad = (lane >> 4);
    const int l15  = lane & 15;

    // ---- 9 serial squarings, each: 24 MFMA/wave + hi/lo plane rewrite.
    for (int k = 1; k < NK; ++k) {
        __syncthreads();                       // planes ready
        f32x4 acc[4];
        #pragma unroll
        for (int c = 0; c < 4; ++c) acc[c] = (f32x4){0.f, 0.f, 0.f, 0.f};
        #pragma unroll
        for (int kk = 0; kk < 2; ++kk) {
            const int ao = (16 * wid + l15) * PS + 32 * kk + quad * 8;
            bf16x8 ah = *(const bf16x8*)&Ah[ao];
            bf16x8 al = *(const bf16x8*)&Al[ao];
            #pragma unroll
            for (int c = 0; c < 4; ++c) {
                const int bo = (16 * c + l15) * PS + 32 * kk + quad * 8;
                bf16x8 bh = *(const bf16x8*)&Th[bo];
                bf16x8 bl = *(const bf16x8*)&Tl[bo];
                acc[c] = __builtin_amdgcn_mfma_f32_16x16x32_bf16(ah, bh, acc[c], 0, 0, 0);
                acc[c] = __builtin_amdgcn_mfma_f32_16x16x32_bf16(ah, bl, acc[c], 0, 0, 0);
                acc[c] = __builtin_amdgcn_mfma_f32_16x16x32_bf16(al, bh, acc[c], 0, 0, 0);
            }
        }
        float m = 0.f;
        #pragma unroll
        for (int c = 0; c < 4; ++c)
            #pragma unroll
            for (int r = 0; r < 4; ++r) m = fmaxf(m, acc[c][r]);
        #pragma unroll
        for (int off = 32; off > 0; off >>= 1)
            m = fmaxf(m, __shfl_xor(m, off, 64));
        if (lane == 0) red4[wid] = m;
        __syncthreads();
        const float sc = 1.f / fmaxf(fmaxf(red4[0], red4[1]), fmaxf(red4[2], red4[3]));
        float* Mk  = M  + (k << 12);
        float* Mtk = Mt + (k << 12);
        #pragma unroll
        for (int c = 0; c < 4; ++c) {
            #pragma unroll
            for (int r = 0; r < 4; ++r) {
                float val = acc[c][r] * sc;
                const int rr = 16 * wid + quad * 4 + r;   // C/D: row = quad*4+reg (m89)
                const int cc = 16 * c   + l15;            //      col = lane&15
                Mk [rr * 64 + cc] = val;
                Mtk[cc * 64 + rr] = val;
                if (k < NK - 1) {
                    unsigned short hi = f2bf(val);
                    unsigned short lo = f2bf(val - bf2f(hi));
                    Ah[rr * PS + cc] = hi;  Al[rr * PS + cc] = lo;
                    Th[cc * PS + rr] = hi;  Tl[cc * PS + rr] = lo;
                }
            }
        }
    }
}

// 1024 blocks x 128 threads: wave 0 -> p_t, wave 1 -> q_t, softmax row, then both waves
// broadcast-write the row to all 256 batches (64 KB per block, write-roofline bound).
__global__ __launch_bounds__(128) void hmm_fused(const float* __restrict__ M,
                                                 const float* __restrict__ Mt,
                                                 const float* __restrict__ logInit,
                                                 float* __restrict__ out) {
    const int t = blockIdx.x;
    __shared__ float sp[64];
    __shared__ float sq[64];
    __shared__ float sg[64];
    const int lane = threadIdx.x & 63;
    const int w    = threadIdx.x >> 6;

    if (w == 0) {
        sp[lane] = __expf(logInit[lane]);
        const int e = t;
        for (int k = 0; k < NK; ++k) {
            if ((e >> k) & 1) {
                const float* Mk = M + (k << 12);
                float a0 = 0.f, a1 = 0.f, a2 = 0.f, a3 = 0.f;
                #pragma unroll
                for (int i = 0; i < 16; ++i) {
                    a0 = fmaf(sp[i],      Mk[( i       << 6) + lane], a0);
                    a1 = fmaf(sp[i + 16], Mk[((i + 16) << 6) + lane], a1);
                    a2 = fmaf(sp[i + 32], Mk[((i + 32) << 6) + lane], a2);
                    a3 = fmaf(sp[i + 48], Mk[((i + 48) << 6) + lane], a3);
                }
                float acc = (a0 + a1) + (a2 + a3);
                float mx = acc;
                #pragma unroll
                for (int off = 32; off > 0; off >>= 1)
                    mx = fmaxf(mx, __shfl_xor(mx, off, 64));
                sp[lane] = acc * (1.f / mx);
            }
        }
    } else {
        sq[lane] = 1.f;
        const int e = (TT - 1) - t;
        for (int k = 0; k < NK; ++k) {
            if ((e >> k) & 1) {
                const float* Mk = Mt + (k << 12);
                float a0 = 0.f, a1 = 0.f, a2 = 0.f, a3 = 0.f;
                #pragma unroll
                for (int i = 0; i < 16; ++i) {
                    a0 = fmaf(sq[i],      Mk[( i       << 6) + lane], a0);
                    a1 = fmaf(sq[i + 16], Mk[((i + 16) << 6) + lane], a1);
                    a2 = fmaf(sq[i + 32], Mk[((i + 32) << 6) + lane], a2);
                    a3 = fmaf(sq[i + 48], Mk[((i + 48) << 6) + lane], a3);
                }
                float acc = (a0 + a1) + (a2 + a3);
                float mx = acc;
                #pragma unroll
                for (int off = 32; off > 0; off >>= 1)
                    mx = fmaxf(mx, __shfl_xor(mx, off, 64));
                sq[lane] = acc * (1.f / mx);
            }
        }
    }
    __syncthreads();

    if (w == 0) {
        float gv = __logf(sp[lane]) + __logf(sq[lane]);
        float mx = gv;
        #pragma unroll
        for (int off = 32; off > 0; off >>= 1)
            mx = fmaxf(mx, __shfl_xor(mx, off, 64));
        float ex = __expf(gv - mx);
        float sm = ex;
        #pragma unroll
        for (int off = 32; off > 0; off >>= 1)
            sm += __shfl_xor(sm, off, 64);
        sg[lane] = gv - mx - __logf(sm);
    }
    __syncthreads();

    // Broadcast row t to all 256 batches: out[b][t][0..63], 256-B chunks, float4.
    const int s4 = threadIdx.x & 15;
    const int b0 = threadIdx.x >> 4;                 // 0..7
    float4 val = ((const float4*)sg)[s4];
    float4* o4 = (float4*)out;
    const size_t trow = (size_t)t * 16 + s4;
    #pragma unroll
    for (int it = 0; it < 32; ++it) {
        int b = (it << 3) + b0;
        o4[(size_t)b * 16384 + trow] = val;
    }
}

extern "C" void kernel_launch(void* const* d_in, const int* in_sizes, int n_in,
                              void* d_out, int out_size, void* d_ws, size_t ws_size,
                              hipStream_t stream) {
    // inputs: [0] observations (unused), [1] log_transition (64x64 f32),
    //         [2] log_initial (64 f32), [3] log_emission (unused)
    const float* logA    = (const float*)d_in[1];
    const float* logInit = (const float*)d_in[2];
    float* M  = (float*)d_ws;              // 10 * 4096 floats
    float* Mt = M + NK * 4096;             // 10 * 4096 floats (320 KB of ws)
    hmm_powers<<<1, 256, 0, stream>>>(logA, M, Mt);
    hmm_fused<<<TT, 128, 0, stream>>>(M, Mt, logInit, (float*)d_out);
}